// Round 3
// baseline (653.787 us; speedup 1.0000x reference)
//
#include <hip/hip_runtime.h>
#include <hip/hip_bf16.h>

#define HID 128
#define NGRAPH 512
#define IN_DIM 384

typedef __attribute__((ext_vector_type(2))) float f32x2;

// ---------------- degree ----------------
__global__ void deg_kernel(const int* __restrict__ dst, int* __restrict__ deg, int E) {
    int e = blockIdx.x * blockDim.x + threadIdx.x;
    if (e < E) atomicAdd(&deg[dst[e]], 1);
}

__global__ void dis_kernel(const int* __restrict__ deg, float* __restrict__ dis, int n) {
    int v = blockIdx.x * blockDim.x + threadIdx.x;
    if (v < n) dis[v] = rsqrtf((float)(deg[v] + 1));  // +1 = self-loop
}

// ---------------- exclusive scan of deg -> row_start ----------------
__global__ __launch_bounds__(256) void scan_part(const int* __restrict__ deg, int* __restrict__ row,
                                                 int* __restrict__ blockSums, int n) {
    __shared__ int ts[256];
    const int b = blockIdx.x, t = threadIdx.x;
    const int base = b * 1024 + t * 4;
    int v0 = (base + 0 < n) ? deg[base + 0] : 0;
    int v1 = (base + 1 < n) ? deg[base + 1] : 0;
    int v2 = (base + 2 < n) ? deg[base + 2] : 0;
    int v3 = (base + 3 < n) ? deg[base + 3] : 0;
    const int s = v0 + v1 + v2 + v3;
    ts[t] = s;
    __syncthreads();
    for (int off = 1; off < 256; off <<= 1) {
        int x = (t >= off) ? ts[t - off] : 0;
        __syncthreads();
        ts[t] += x;
        __syncthreads();
    }
    int p = ts[t] - s;
    if (base + 0 < n) { row[base + 0] = p; p += v0; }
    if (base + 1 < n) { row[base + 1] = p; p += v1; }
    if (base + 2 < n) { row[base + 2] = p; p += v2; }
    if (base + 3 < n) { row[base + 3] = p; }
    if (t == 255) blockSums[b] = ts[255];
}

__global__ void scan_tops(int* __restrict__ blockSums, int nb) {
    if (threadIdx.x == 0 && blockIdx.x == 0) {
        int acc = 0;
        for (int i = 0; i < nb; i++) { int v = blockSums[i]; blockSums[i] = acc; acc += v; }
    }
}

__global__ __launch_bounds__(256) void scan_add(int* __restrict__ row, int* __restrict__ cursor,
                                                const int* __restrict__ blockSums, int n, int E) {
    const int b = blockIdx.x, t = threadIdx.x;
    const int off = blockSums[b];
    const int base = b * 1024 + t * 4;
#pragma unroll
    for (int j = 0; j < 4; j++) {
        int i = base + j;
        if (i < n) { int v = row[i] + off; row[i] = v; cursor[i] = v; }
    }
    if (b == 0 && t == 0) row[n] = E;
}

// ---------------- CSR fill (ushort src ids, dst-range sweep) ----------------
__global__ void fill_kernel(const int* __restrict__ src, const int* __restrict__ dst,
                            int* __restrict__ cursor, unsigned short* __restrict__ csr16,
                            int E, int lo, int hi) {
    int e = blockIdx.x * blockDim.x + threadIdx.x;
    if (e < E) {
        const int d = dst[e];
        if (d >= lo && d < hi) {
            int pos = atomicAdd(&cursor[d], 1);
            csr16[pos] = (unsigned short)src[e];
        }
    }
}

// ---- tiled register-blocked GEMM: hs8[v,:] = fp8_e4m3( (X[v,:] @ W) * dis[v] * 8 ) ----
template <int K>
__global__ __launch_bounds__(256) void gemm_tile(const float* __restrict__ X,
                                                 const float* __restrict__ W,
                                                 const float* __restrict__ dis,
                                                 unsigned int* __restrict__ out8, int n) {
    constexpr int KC = 32;
    __shared__ float asT[KC][68];
    __shared__ float bs[KC * HID];
    const int t = threadIdx.x;
    const int tx = t & 31;   // col quad
    const int ty = t >> 5;   // row group
    const int row0 = blockIdx.x * 64;

    float4 acc[8];
#pragma unroll
    for (int j = 0; j < 8; j++) acc[j] = make_float4(0.f, 0.f, 0.f, 0.f);

    const int ar = t >> 3;
    const int af = t & 7;

    for (int k0 = 0; k0 < K; k0 += KC) {
#pragma unroll
        for (int half = 0; half < 2; half++) {
            const int r = ar + half * 32;
            const int gr = row0 + r;
            float4 a = make_float4(0.f, 0.f, 0.f, 0.f);
            if (gr < n) a = *(const float4*)&X[(long)gr * K + k0 + af * 4];
            asT[af * 4 + 0][r] = a.x;
            asT[af * 4 + 1][r] = a.y;
            asT[af * 4 + 2][r] = a.z;
            asT[af * 4 + 3][r] = a.w;
        }
        {
            const float4* wp = (const float4*)&W[(long)k0 * HID];
            float4* bp = (float4*)bs;
#pragma unroll
            for (int i = 0; i < 4; i++) bp[t + i * 256] = wp[t + i * 256];
        }
        __syncthreads();
#pragma unroll 8
        for (int kk = 0; kk < KC; kk++) {
            const float4 a0 = *(const float4*)&asT[kk][ty * 8];
            const float4 a1 = *(const float4*)&asT[kk][ty * 8 + 4];
            const float4 b  = *(const float4*)&bs[kk * HID + tx * 4];
            acc[0].x = fmaf(a0.x, b.x, acc[0].x); acc[0].y = fmaf(a0.x, b.y, acc[0].y);
            acc[0].z = fmaf(a0.x, b.z, acc[0].z); acc[0].w = fmaf(a0.x, b.w, acc[0].w);
            acc[1].x = fmaf(a0.y, b.x, acc[1].x); acc[1].y = fmaf(a0.y, b.y, acc[1].y);
            acc[1].z = fmaf(a0.y, b.z, acc[1].z); acc[1].w = fmaf(a0.y, b.w, acc[1].w);
            acc[2].x = fmaf(a0.z, b.x, acc[2].x); acc[2].y = fmaf(a0.z, b.y, acc[2].y);
            acc[2].z = fmaf(a0.z, b.z, acc[2].z); acc[2].w = fmaf(a0.z, b.w, acc[2].w);
            acc[3].x = fmaf(a0.w, b.x, acc[3].x); acc[3].y = fmaf(a0.w, b.y, acc[3].y);
            acc[3].z = fmaf(a0.w, b.z, acc[3].z); acc[3].w = fmaf(a0.w, b.w, acc[3].w);
            acc[4].x = fmaf(a1.x, b.x, acc[4].x); acc[4].y = fmaf(a1.x, b.y, acc[4].y);
            acc[4].z = fmaf(a1.x, b.z, acc[4].z); acc[4].w = fmaf(a1.x, b.w, acc[4].w);
            acc[5].x = fmaf(a1.y, b.x, acc[5].x); acc[5].y = fmaf(a1.y, b.y, acc[5].y);
            acc[5].z = fmaf(a1.y, b.z, acc[5].z); acc[5].w = fmaf(a1.y, b.w, acc[5].w);
            acc[6].x = fmaf(a1.z, b.x, acc[6].x); acc[6].y = fmaf(a1.z, b.y, acc[6].y);
            acc[6].z = fmaf(a1.z, b.z, acc[6].z); acc[6].w = fmaf(a1.z, b.w, acc[6].w);
            acc[7].x = fmaf(a1.w, b.x, acc[7].x); acc[7].y = fmaf(a1.w, b.y, acc[7].y);
            acc[7].z = fmaf(a1.w, b.z, acc[7].z); acc[7].w = fmaf(a1.w, b.w, acc[7].w);
        }
        __syncthreads();
    }

#pragma unroll
    for (int j = 0; j < 8; j++) {
        const int v = row0 + ty * 8 + j;
        if (v < n) {
            const float s = dis[v] * 8.0f;   // x8 keeps layer-2 messages out of e4m3 subnormals
            int w01 = __builtin_amdgcn_cvt_pk_fp8_f32(acc[j].x * s, acc[j].y * s, 0, false);
            int w   = __builtin_amdgcn_cvt_pk_fp8_f32(acc[j].z * s, acc[j].w * s, w01, true);
            out8[(long)v * (HID / 4) + tx] = (unsigned int)w;
        }
    }
}

// ---------------- gather aggregation + finalize (+ optional fused pool) ----------------
// v3 (resubmit after infra failure): TWO nodes per 64-lane wave (32 lanes each) to
// amortize the per-wave serial chain (row-ptr RT -> csr RT -> gather RT -> fold ->
// epilogue) over 2 nodes. Kernel was wave-level latency-bound: ~48 CU-cyc/edge with
// all pipes <25%. Each gather instruction still touches 8 distinct 128B rows (4 edges
// of node A + 4 of node B) -> identical VALU/edge and line/edge cost; serialized
// latency per node ~halved. Fold is 2 shfl levels (xor 8,16) instead of 3.
template <bool POOL>
__global__ __launch_bounds__(256) void agg_kernel(const unsigned char* __restrict__ hs8,
                                                  const unsigned short* __restrict__ csr16,
                                                  const int* __restrict__ row,
                                                  const float* __restrict__ dis,
                                                  const float* __restrict__ bias,
                                                  const int* __restrict__ batch,
                                                  float* __restrict__ buf,
                                                  float* __restrict__ sums,
                                                  int* __restrict__ cnt, int n) {
    const int wave = threadIdx.x >> 6;
    const int lane = threadIdx.x & 63;
    const int h    = lane >> 5;       // node half within wave (0/1)
    const int l32  = lane & 31;       // lane within node
    const int sub  = l32 >> 3;        // edge slot within pass (0..3)
    const int lc   = l32 & 7;         // 16-byte chunk within row (0..7)

    const int vb = blockIdx.x * 8 + wave * 2;
    if (vb >= n) return;              // whole-wave guard
    int v = vb + h;
    const bool vok = (v < n);
    if (!vok) v = n - 1;              // clamped duplicate; stores masked by vok

    const int rs = row[v];
    const int re = row[v + 1];

    // hoisted epilogue inputs (overlap their latency with the edge loop)
    const int col = (lc << 4) + (sub << 2);       // this lane owns cols col..col+3
    const unsigned int selfw = *(const unsigned int*)&hs8[(long)v * HID + col];
    const float dv = dis[v] * 0.125f;             // undo the x8 message scale
    const float4 bq = *(const float4*)&bias[col];
    int g = 0;
    if (POOL) g = batch[v];

    float acc[16];
#pragma unroll
    for (int i = 0; i < 16; i++) acc[i] = 0.f;

    // wave-uniform window count = max over the two halves
    int win = (re - rs + 31) >> 5;
    { int other = __shfl_xor(win, 32, 64); win = win > other ? win : other; }
    const int last = (re > rs) ? (re - 1) : 0;    // safe clamp index (csr16[0] always valid)

    for (int wnd = 0; wnd < win; ++wnd) {
        const int base = rs + (wnd << 5);
        // one load instruction fetches 32 indices per node (both halves at once)
        int ei = base + l32;
        if (ei > last) ei = last;
        const int myidx = (int)__builtin_nontemporal_load(&csr16[ei]);

        uint4 w[8];
#pragma unroll
        for (int p = 0; p < 8; p++) {
            const int pe = base + (p << 2);       // half-uniform guard (exec-masked)
            if (pe < re) {
                const int idx = __shfl(myidx, h * 32 + (p << 2) + sub, 64);
                w[p] = *(const uint4*)&hs8[(long)idx * HID + (lc << 4)];
            } else {
                w[p] = make_uint4(0u, 0u, 0u, 0u);
            }
        }
#pragma unroll
        for (int p = 0; p < 8; p++) {
            if (base + (p << 2) + sub < re) {     // per-lane validity
                const uint4 ww = w[p];
                f32x2 u;
                u = __builtin_amdgcn_cvt_pk_f32_fp8(ww.x, false); acc[0]  += u.x; acc[1]  += u.y;
                u = __builtin_amdgcn_cvt_pk_f32_fp8(ww.x, true);  acc[2]  += u.x; acc[3]  += u.y;
                u = __builtin_amdgcn_cvt_pk_f32_fp8(ww.y, false); acc[4]  += u.x; acc[5]  += u.y;
                u = __builtin_amdgcn_cvt_pk_f32_fp8(ww.y, true);  acc[6]  += u.x; acc[7]  += u.y;
                u = __builtin_amdgcn_cvt_pk_f32_fp8(ww.z, false); acc[8]  += u.x; acc[9]  += u.y;
                u = __builtin_amdgcn_cvt_pk_f32_fp8(ww.z, true);  acc[10] += u.x; acc[11] += u.y;
                u = __builtin_amdgcn_cvt_pk_f32_fp8(ww.w, false); acc[12] += u.x; acc[13] += u.y;
                u = __builtin_amdgcn_cvt_pk_f32_fp8(ww.w, true);  acc[14] += u.x; acc[15] += u.y;
            }
        }
    }

    // fold the 4 sub-groups within each half (lanes differing in bits 3..4, same lc)
#pragma unroll
    for (int i = 0; i < 16; i++) {
        acc[i] += __shfl_xor(acc[i], 8, 64);
        acc[i] += __shfl_xor(acc[i], 16, 64);
    }

    // lane owns cols col..col+3  ->  acc[4*sub + j] + self contribution
    f32x2 s01 = __builtin_amdgcn_cvt_pk_f32_fp8(selfw, false);
    f32x2 s23 = __builtin_amdgcn_cvt_pk_f32_fp8(selfw, true);
    const float r0 = fmaxf(fmaf(dv, acc[(sub << 2) + 0] + s01.x, bq.x), 0.f);
    const float r1 = fmaxf(fmaf(dv, acc[(sub << 2) + 1] + s01.y, bq.y), 0.f);
    const float r2 = fmaxf(fmaf(dv, acc[(sub << 2) + 2] + s23.x, bq.z), 0.f);
    const float r3 = fmaxf(fmaf(dv, acc[(sub << 2) + 3] + s23.y, bq.w), 0.f);

    if (vok) {
        if (POOL) {
            unsafeAtomicAdd(&sums[g * HID + col + 0], r0);
            unsafeAtomicAdd(&sums[g * HID + col + 1], r1);
            unsafeAtomicAdd(&sums[g * HID + col + 2], r2);
            unsafeAtomicAdd(&sums[g * HID + col + 3], r3);
            if (l32 == 0) atomicAdd(&cnt[g], 1);
        } else {
            float4 r; r.x = r0; r.y = r1; r.z = r2; r.w = r3;
            *(float4*)&buf[(long)v * HID + col] = r;
        }
    }
}

// ---------------- mean + MLP head ----------------
__global__ __launch_bounds__(64) void mlp_kernel(const float* __restrict__ sums,
                                                 const int* __restrict__ cnt,
                                                 const float* __restrict__ Wl1,
                                                 const float* __restrict__ bl1,
                                                 const float* __restrict__ Wl2,
                                                 const float* __restrict__ bl2,
                                                 float* __restrict__ out) {
    const int g = blockIdx.x, t = threadIdx.x;
    __shared__ float mean[HID];
    __shared__ float hid[64];
    const float c = fmaxf((float)cnt[g], 1.0f);
    mean[t] = sums[g * HID + t] / c;
    mean[t + 64] = sums[g * HID + 64 + t] / c;
    __syncthreads();
    float acc = bl1[t];
#pragma unroll 4
    for (int k = 0; k < HID; k++) acc = fmaf(mean[k], Wl1[k * 64 + t], acc);
    hid[t] = fmaxf(acc, 0.f);
    __syncthreads();
    if (t < 5) {
        float a = bl2[t];
#pragma unroll 4
        for (int k = 0; k < 64; k++) a = fmaf(hid[k], Wl2[k * 5 + t], a);
        out[g * 5 + t] = 1.f / (1.f + expf(-a));
    }
}

extern "C" void kernel_launch(void* const* d_in, const int* in_sizes, int n_in,
                              void* d_out, int out_size, void* d_ws, size_t ws_size,
                              hipStream_t stream) {
    const float* x   = (const float*)d_in[0];
    const int* ei    = (const int*)d_in[1];
    const int* batch = (const int*)d_in[2];
    const float* W1  = (const float*)d_in[3];
    const float* b1  = (const float*)d_in[4];
    const float* W2  = (const float*)d_in[5];
    const float* b2  = (const float*)d_in[6];
    const float* Wl1 = (const float*)d_in[7];
    const float* bl1 = (const float*)d_in[8];
    const float* Wl2 = (const float*)d_in[9];
    const float* bl2 = (const float*)d_in[10];
    float* out = (float*)d_out;

    const int n = in_sizes[0] / IN_DIM;       // 50000
    const int E = in_sizes[1] / 2;            // 1600000
    const int* src = ei;
    const int* dst = ei + E;

    char* ws = (char*)d_ws;
    size_t off = 0;
    auto alloc = [&](size_t bytes) {
        void* p = ws + off;
        off = (off + bytes + 255) & ~(size_t)255;
        return p;
    };
    int*   deg       = (int*)alloc((size_t)n * 4);
    float* dis       = (float*)alloc((size_t)n * 4);
    int*   row       = (int*)alloc((size_t)(n + 1) * 4);
    int*   cursor    = (int*)alloc((size_t)n * 4);
    unsigned short* csr16 = (unsigned short*)alloc((size_t)E * 2);
    int*   blockSums = (int*)alloc(256 * 4);
    unsigned char* hs8 = (unsigned char*)alloc((size_t)n * HID);       // fp8 messages
    float* buf1 = (float*)alloc((size_t)n * HID * 4);                  // fp32 inter-layer h
    float* sums = (float*)alloc((size_t)NGRAPH * HID * 4);
    int*   cnt  = (int*)alloc((size_t)NGRAPH * 4);
    (void)ws_size;

    const int nb = (n + 1023) / 1024;
    const int gemmBlocks = (n + 63) / 64;
    const int aggBlocks  = (n + 7) / 8;       // 8 nodes per block (2 per wave)
    const int edgeBlocks = (E + 255) / 256;

    // --- degree / norm / CSR ---
    hipMemsetAsync(deg, 0, (size_t)n * 4, stream);
    deg_kernel<<<edgeBlocks, 256, 0, stream>>>(dst, deg, E);
    dis_kernel<<<(n + 255) / 256, 256, 0, stream>>>(deg, dis, n);
    scan_part<<<nb, 256, 0, stream>>>(deg, row, blockSums, n);
    scan_tops<<<1, 64, 0, stream>>>(blockSums, nb);
    scan_add<<<nb, 256, 0, stream>>>(row, cursor, blockSums, n, E);
    // 4 dst-range sweeps keep csr16 writes L2-resident (low writeback amplification)
    {
        const int step = (n + 3) / 4;
        for (int k = 0; k < 4; k++) {
            const int lo = k * step;
            const int hi = (k == 3) ? n : (lo + step);
            fill_kernel<<<edgeBlocks, 256, 0, stream>>>(src, dst, cursor, csr16, E, lo, hi);
        }
    }

    // --- conv1 ---
    gemm_tile<IN_DIM><<<gemmBlocks, 256, 0, stream>>>(x, W1, dis, (unsigned int*)hs8, n);
    agg_kernel<false><<<aggBlocks, 256, 0, stream>>>(hs8, csr16, row, dis, b1, batch,
                                                     buf1, nullptr, nullptr, n);

    // --- conv2 (pool fused) ---
    gemm_tile<HID><<<gemmBlocks, 256, 0, stream>>>(buf1, W2, dis, (unsigned int*)hs8, n);
    hipMemsetAsync(sums, 0, (size_t)NGRAPH * HID * 4, stream);
    hipMemsetAsync(cnt, 0, (size_t)NGRAPH * 4, stream);
    agg_kernel<true><<<aggBlocks, 256, 0, stream>>>(hs8, csr16, row, dis, b2, batch,
                                                    nullptr, sums, cnt, n);

    // --- head ---
    mlp_kernel<<<NGRAPH, 64, 0, stream>>>(sums, cnt, Wl1, bl1, Wl2, bl2, out);
}

// Round 4
// 586.023 us; speedup vs baseline: 1.1156x; 1.1156x over previous
//
#include <hip/hip_runtime.h>
#include <hip/hip_bf16.h>
#include <string.h>

#define HID 128
#define NGRAPH 512
#define IN_DIM 384

typedef __attribute__((ext_vector_type(2))) float f32x2;

__device__ __forceinline__ float bf2f(unsigned short u) {
    unsigned int x = ((unsigned int)u) << 16;
    float f; __builtin_memcpy(&f, &x, 4); return f;
}
__device__ __forceinline__ unsigned short f2bf(float f) {
    unsigned int b; __builtin_memcpy(&b, &f, 4);
    unsigned int r = (b + 0x7FFFu + ((b >> 16) & 1u)) >> 16;   // RNE
    return (unsigned short)r;
}

// ---------------- degree ----------------
__global__ void deg_kernel(const int* __restrict__ dst, int* __restrict__ deg, int E) {
    int e = blockIdx.x * blockDim.x + threadIdx.x;
    if (e < E) atomicAdd(&deg[dst[e]], 1);
}

__global__ void dis_kernel(const int* __restrict__ deg, float* __restrict__ dis, int n) {
    int v = blockIdx.x * blockDim.x + threadIdx.x;
    if (v < n) dis[v] = rsqrtf((float)(deg[v] + 1));  // +1 = self-loop
}

// ---------------- exclusive scan of deg -> row_start ----------------
__global__ __launch_bounds__(256) void scan_part(const int* __restrict__ deg, int* __restrict__ row,
                                                 int* __restrict__ blockSums, int n) {
    __shared__ int ts[256];
    const int b = blockIdx.x, t = threadIdx.x;
    const int base = b * 1024 + t * 4;
    int v0 = (base + 0 < n) ? deg[base + 0] : 0;
    int v1 = (base + 1 < n) ? deg[base + 1] : 0;
    int v2 = (base + 2 < n) ? deg[base + 2] : 0;
    int v3 = (base + 3 < n) ? deg[base + 3] : 0;
    const int s = v0 + v1 + v2 + v3;
    ts[t] = s;
    __syncthreads();
    for (int off = 1; off < 256; off <<= 1) {
        int x = (t >= off) ? ts[t - off] : 0;
        __syncthreads();
        ts[t] += x;
        __syncthreads();
    }
    int p = ts[t] - s;
    if (base + 0 < n) { row[base + 0] = p; p += v0; }
    if (base + 1 < n) { row[base + 1] = p; p += v1; }
    if (base + 2 < n) { row[base + 2] = p; p += v2; }
    if (base + 3 < n) { row[base + 3] = p; }
    if (t == 255) blockSums[b] = ts[255];
}

__global__ void scan_tops(int* __restrict__ blockSums, int nb) {
    if (threadIdx.x == 0 && blockIdx.x == 0) {
        int acc = 0;
        for (int i = 0; i < nb; i++) { int v = blockSums[i]; blockSums[i] = acc; acc += v; }
    }
}

__global__ __launch_bounds__(256) void scan_add(int* __restrict__ row, int* __restrict__ cursor,
                                                const int* __restrict__ blockSums, int n, int E) {
    const int b = blockIdx.x, t = threadIdx.x;
    const int off = blockSums[b];
    const int base = b * 1024 + t * 4;
#pragma unroll
    for (int j = 0; j < 4; j++) {
        int i = base + j;
        if (i < n) { int v = row[i] + off; row[i] = v; cursor[i] = v; }
    }
    if (b == 0 && t == 0) row[n] = E;
}

// ---------------- CSR fill (ushort src ids, dst-range sweep) ----------------
__global__ void fill_kernel(const int* __restrict__ src, const int* __restrict__ dst,
                            int* __restrict__ cursor, unsigned short* __restrict__ csr16,
                            int E, int lo, int hi) {
    int e = blockIdx.x * blockDim.x + threadIdx.x;
    if (e < E) {
        const int d = dst[e];
        if (d >= lo && d < hi) {
            int pos = atomicAdd(&cursor[d], 1);
            csr16[pos] = (unsigned short)src[e];
        }
    }
}

// ---- tiled register-blocked GEMM: hs8[v,:] = fp8_e4m3( (X[v,:] @ W) * dis[v] * 8 ) ----
// BF16IN: X is bf16 [n][K] (the inter-layer buffer); converted to f32 during LDS
// staging so the fp32 inner loop is unchanged.
template <int K, bool BF16IN>
__global__ __launch_bounds__(256) void gemm_tile(const void* __restrict__ Xv,
                                                 const float* __restrict__ W,
                                                 const float* __restrict__ dis,
                                                 unsigned int* __restrict__ out8, int n) {
    constexpr int KC = 32;
    __shared__ float asT[KC][68];
    __shared__ float bs[KC * HID];
    const int t = threadIdx.x;
    const int tx = t & 31;   // col quad
    const int ty = t >> 5;   // row group
    const int row0 = blockIdx.x * 64;

    float4 acc[8];
#pragma unroll
    for (int j = 0; j < 8; j++) acc[j] = make_float4(0.f, 0.f, 0.f, 0.f);

    const int ar = t >> 3;
    const int af = t & 7;

    for (int k0 = 0; k0 < K; k0 += KC) {
#pragma unroll
        for (int half = 0; half < 2; half++) {
            const int r = ar + half * 32;
            const int gr = row0 + r;
            float4 a = make_float4(0.f, 0.f, 0.f, 0.f);
            if (gr < n) {
                if constexpr (BF16IN) {
                    const ushort4 u = *(const ushort4*)((const unsigned short*)Xv + (long)gr * K + k0 + af * 4);
                    a.x = bf2f(u.x); a.y = bf2f(u.y); a.z = bf2f(u.z); a.w = bf2f(u.w);
                } else {
                    a = *(const float4*)((const float*)Xv + (long)gr * K + k0 + af * 4);
                }
            }
            asT[af * 4 + 0][r] = a.x;
            asT[af * 4 + 1][r] = a.y;
            asT[af * 4 + 2][r] = a.z;
            asT[af * 4 + 3][r] = a.w;
        }
        {
            const float4* wp = (const float4*)&W[(long)k0 * HID];
            float4* bp = (float4*)bs;
#pragma unroll
            for (int i = 0; i < 4; i++) bp[t + i * 256] = wp[t + i * 256];
        }
        __syncthreads();
#pragma unroll 8
        for (int kk = 0; kk < KC; kk++) {
            const float4 a0 = *(const float4*)&asT[kk][ty * 8];
            const float4 a1 = *(const float4*)&asT[kk][ty * 8 + 4];
            const float4 b  = *(const float4*)&bs[kk * HID + tx * 4];
            acc[0].x = fmaf(a0.x, b.x, acc[0].x); acc[0].y = fmaf(a0.x, b.y, acc[0].y);
            acc[0].z = fmaf(a0.x, b.z, acc[0].z); acc[0].w = fmaf(a0.x, b.w, acc[0].w);
            acc[1].x = fmaf(a0.y, b.x, acc[1].x); acc[1].y = fmaf(a0.y, b.y, acc[1].y);
            acc[1].z = fmaf(a0.y, b.z, acc[1].z); acc[1].w = fmaf(a0.y, b.w, acc[1].w);
            acc[2].x = fmaf(a0.z, b.x, acc[2].x); acc[2].y = fmaf(a0.z, b.y, acc[2].y);
            acc[2].z = fmaf(a0.z, b.z, acc[2].z); acc[2].w = fmaf(a0.z, b.w, acc[2].w);
            acc[3].x = fmaf(a0.w, b.x, acc[3].x); acc[3].y = fmaf(a0.w, b.y, acc[3].y);
            acc[3].z = fmaf(a0.w, b.z, acc[3].z); acc[3].w = fmaf(a0.w, b.w, acc[3].w);
            acc[4].x = fmaf(a1.x, b.x, acc[4].x); acc[4].y = fmaf(a1.x, b.y, acc[4].y);
            acc[4].z = fmaf(a1.x, b.z, acc[4].z); acc[4].w = fmaf(a1.x, b.w, acc[4].w);
            acc[5].x = fmaf(a1.y, b.x, acc[5].x); acc[5].y = fmaf(a1.y, b.y, acc[5].y);
            acc[5].z = fmaf(a1.y, b.z, acc[5].z); acc[5].w = fmaf(a1.y, b.w, acc[5].w);
            acc[6].x = fmaf(a1.z, b.x, acc[6].x); acc[6].y = fmaf(a1.z, b.y, acc[6].y);
            acc[6].z = fmaf(a1.z, b.z, acc[6].z); acc[6].w = fmaf(a1.z, b.w, acc[6].w);
            acc[7].x = fmaf(a1.w, b.x, acc[7].x); acc[7].y = fmaf(a1.w, b.y, acc[7].y);
            acc[7].z = fmaf(a1.w, b.z, acc[7].z); acc[7].w = fmaf(a1.w, b.w, acc[7].w);
        }
        __syncthreads();
    }

#pragma unroll
    for (int j = 0; j < 8; j++) {
        const int v = row0 + ty * 8 + j;
        if (v < n) {
            const float s = dis[v] * 8.0f;   // x8 keeps layer-2 messages out of e4m3 subnormals
            int w01 = __builtin_amdgcn_cvt_pk_fp8_f32(acc[j].x * s, acc[j].y * s, 0, false);
            int w   = __builtin_amdgcn_cvt_pk_fp8_f32(acc[j].z * s, acc[j].w * s, w01, true);
            out8[(long)v * (HID / 4) + tx] = (unsigned int)w;
        }
    }
}

// ---------------- gather aggregation + finalize (+ optional fused pool) ----------------
// Round-0 structure restored (proven 124 us, 32 VGPR): one 64-lane wave per dst node;
// 8 lanes/edge x 16 B, 8 edges/pass, 4 passes unrolled. Change vs round-0: the
// inter-layer buffer is written as PACKED BF16 (2 cols -> one u32 store), halving
// agg<false>'s write traffic (25.6 -> 12.8 MB) and gemm2's read traffic. Theory: agg
// is pinned at a ~0.9 TB/s beyond-L2 random-line service ceiling (v0: 843 GB/s,
// v3: 1.04 TB/s at 2x bytes) -> cut bytes, not latency.
template <bool POOL>
__global__ __launch_bounds__(256) void agg_kernel(const unsigned char* __restrict__ hs8,
                                                  const unsigned short* __restrict__ csr16,
                                                  const int* __restrict__ row,
                                                  const float* __restrict__ dis,
                                                  const float* __restrict__ bias,
                                                  const int* __restrict__ batch,
                                                  unsigned int* __restrict__ buf,   // bf16x2 packed
                                                  float* __restrict__ sums,
                                                  int* __restrict__ cnt, int n) {
    const int v = blockIdx.x * 4 + (threadIdx.x >> 6);
    if (v >= n) return;
    const int lane = threadIdx.x & 63;
    const int sub = lane >> 3;      // edge slot within pass (0..7)
    const int lc  = lane & 7;       // 16-byte chunk within row

    const int rs = row[v];
    const int re = row[v + 1];

    float acc[16];
#pragma unroll
    for (int i = 0; i < 16; i++) acc[i] = 0.f;

    for (int base = rs; base < re; base += 32) {
        uint4 w[4];
        int vld[4];
#pragma unroll
        for (int p = 0; p < 4; p++) {
            const int pe = base + p * 8;
            if (pe < re) {                       // wave-uniform guard
                const int ei = pe + sub;
                const int idx = __builtin_nontemporal_load(&csr16[(ei < re) ? ei : (re - 1)]);
                w[p] = *(const uint4*)&hs8[(long)idx * HID + (lc << 4)];
                vld[p] = (ei < re);
            } else {
                w[p] = make_uint4(0u, 0u, 0u, 0u);
                vld[p] = 0;
            }
        }
#pragma unroll
        for (int p = 0; p < 4; p++) {
            if (vld[p]) {
                const uint4 ww = w[p];
                f32x2 u;
                u = __builtin_amdgcn_cvt_pk_f32_fp8(ww.x, false); acc[0]  += u.x; acc[1]  += u.y;
                u = __builtin_amdgcn_cvt_pk_f32_fp8(ww.x, true);  acc[2]  += u.x; acc[3]  += u.y;
                u = __builtin_amdgcn_cvt_pk_f32_fp8(ww.y, false); acc[4]  += u.x; acc[5]  += u.y;
                u = __builtin_amdgcn_cvt_pk_f32_fp8(ww.y, true);  acc[6]  += u.x; acc[7]  += u.y;
                u = __builtin_amdgcn_cvt_pk_f32_fp8(ww.z, false); acc[8]  += u.x; acc[9]  += u.y;
                u = __builtin_amdgcn_cvt_pk_f32_fp8(ww.z, true);  acc[10] += u.x; acc[11] += u.y;
                u = __builtin_amdgcn_cvt_pk_f32_fp8(ww.w, false); acc[12] += u.x; acc[13] += u.y;
                u = __builtin_amdgcn_cvt_pk_f32_fp8(ww.w, true);  acc[14] += u.x; acc[15] += u.y;
            }
        }
    }

    // fold the 8 sub-groups (lanes differing in bits 3..5, same lc)
#pragma unroll
    for (int i = 0; i < 16; i++) {
        acc[i] += __shfl_xor(acc[i], 8, 64);
        acc[i] += __shfl_xor(acc[i], 16, 64);
        acc[i] += __shfl_xor(acc[i], 32, 64);
    }

    // each lane owns cols col, col+1 where col = 16*lc + 2*sub
    const int col = (lc << 4) + (sub << 1);
    const unsigned short selfw = *(const unsigned short*)&hs8[(long)v * HID + col];
    f32x2 sf = __builtin_amdgcn_cvt_pk_f32_fp8((unsigned int)selfw, false);
    const float sx = acc[(sub << 1) + 0] + sf.x;
    const float sy = acc[(sub << 1) + 1] + sf.y;
    const float dv = dis[v] * 0.125f;   // undo the x8 message scale
    const float rx = fmaxf(fmaf(dv, sx, bias[col]), 0.f);
    const float ry = fmaxf(fmaf(dv, sy, bias[col + 1]), 0.f);
    if (POOL) {
        const int g = batch[v];
        unsafeAtomicAdd(&sums[g * HID + col], rx);
        unsafeAtomicAdd(&sums[g * HID + col + 1], ry);
        if (lane == 0) atomicAdd(&cnt[g], 1);
    } else {
        const unsigned int pk = (unsigned int)f2bf(rx) | ((unsigned int)f2bf(ry) << 16);
        buf[(long)v * (HID / 2) + (col >> 1)] = pk;      // col is even
    }
}

// ---------------- mean + MLP head ----------------
__global__ __launch_bounds__(64) void mlp_kernel(const float* __restrict__ sums,
                                                 const int* __restrict__ cnt,
                                                 const float* __restrict__ Wl1,
                                                 const float* __restrict__ bl1,
                                                 const float* __restrict__ Wl2,
                                                 const float* __restrict__ bl2,
                                                 float* __restrict__ out) {
    const int g = blockIdx.x, t = threadIdx.x;
    __shared__ float mean[HID];
    __shared__ float hid[64];
    const float c = fmaxf((float)cnt[g], 1.0f);
    mean[t] = sums[g * HID + t] / c;
    mean[t + 64] = sums[g * HID + 64 + t] / c;
    __syncthreads();
    float acc = bl1[t];
#pragma unroll 4
    for (int k = 0; k < HID; k++) acc = fmaf(mean[k], Wl1[k * 64 + t], acc);
    hid[t] = fmaxf(acc, 0.f);
    __syncthreads();
    if (t < 5) {
        float a = bl2[t];
#pragma unroll 4
        for (int k = 0; k < 64; k++) a = fmaf(hid[k], Wl2[k * 5 + t], a);
        out[g * 5 + t] = 1.f / (1.f + expf(-a));
    }
}

extern "C" void kernel_launch(void* const* d_in, const int* in_sizes, int n_in,
                              void* d_out, int out_size, void* d_ws, size_t ws_size,
                              hipStream_t stream) {
    const float* x   = (const float*)d_in[0];
    const int* ei    = (const int*)d_in[1];
    const int* batch = (const int*)d_in[2];
    const float* W1  = (const float*)d_in[3];
    const float* b1  = (const float*)d_in[4];
    const float* W2  = (const float*)d_in[5];
    const float* b2  = (const float*)d_in[6];
    const float* Wl1 = (const float*)d_in[7];
    const float* bl1 = (const float*)d_in[8];
    const float* Wl2 = (const float*)d_in[9];
    const float* bl2 = (const float*)d_in[10];
    float* out = (float*)d_out;

    const int n = in_sizes[0] / IN_DIM;       // 50000
    const int E = in_sizes[1] / 2;            // 1600000
    const int* src = ei;
    const int* dst = ei + E;

    char* ws = (char*)d_ws;
    size_t off = 0;
    auto alloc = [&](size_t bytes) {
        void* p = ws + off;
        off = (off + bytes + 255) & ~(size_t)255;
        return p;
    };
    int*   deg       = (int*)alloc((size_t)n * 4);
    float* dis       = (float*)alloc((size_t)n * 4);
    int*   row       = (int*)alloc((size_t)(n + 1) * 4);
    int*   cursor    = (int*)alloc((size_t)n * 4);
    unsigned short* csr16 = (unsigned short*)alloc((size_t)E * 2);
    int*   blockSums = (int*)alloc(256 * 4);
    unsigned char* hs8 = (unsigned char*)alloc((size_t)n * HID);       // fp8 messages
    unsigned int* buf1 = (unsigned int*)alloc((size_t)n * HID * 2);    // bf16 inter-layer h
    float* sums = (float*)alloc((size_t)NGRAPH * HID * 4);
    int*   cnt  = (int*)alloc((size_t)NGRAPH * 4);
    (void)ws_size;

    const int nb = (n + 1023) / 1024;
    const int gemmBlocks = (n + 63) / 64;
    const int aggBlocks  = (n + 3) / 4;
    const int edgeBlocks = (E + 255) / 256;

    // --- degree / norm / CSR ---
    hipMemsetAsync(deg, 0, (size_t)n * 4, stream);
    deg_kernel<<<edgeBlocks, 256, 0, stream>>>(dst, deg, E);
    dis_kernel<<<(n + 255) / 256, 256, 0, stream>>>(deg, dis, n);
    scan_part<<<nb, 256, 0, stream>>>(deg, row, blockSums, n);
    scan_tops<<<1, 64, 0, stream>>>(blockSums, nb);
    scan_add<<<nb, 256, 0, stream>>>(row, cursor, blockSums, n, E);
    // 4 dst-range sweeps keep csr16 writes L2-resident (low writeback amplification)
    {
        const int step = (n + 3) / 4;
        for (int k = 0; k < 4; k++) {
            const int lo = k * step;
            const int hi = (k == 3) ? n : (lo + step);
            fill_kernel<<<edgeBlocks, 256, 0, stream>>>(src, dst, cursor, csr16, E, lo, hi);
        }
    }

    // --- conv1 ---
    gemm_tile<IN_DIM, false><<<gemmBlocks, 256, 0, stream>>>(x, W1, dis, (unsigned int*)hs8, n);
    agg_kernel<false><<<aggBlocks, 256, 0, stream>>>(hs8, csr16, row, dis, b1, batch,
                                                     buf1, nullptr, nullptr, n);

    // --- conv2 (pool fused) ---
    gemm_tile<HID, true><<<gemmBlocks, 256, 0, stream>>>(buf1, W2, dis, (unsigned int*)hs8, n);
    hipMemsetAsync(sums, 0, (size_t)NGRAPH * HID * 4, stream);
    hipMemsetAsync(cnt, 0, (size_t)NGRAPH * 4, stream);
    agg_kernel<true><<<aggBlocks, 256, 0, stream>>>(hs8, csr16, row, dis, b2, batch,
                                                    nullptr, sums, cnt, n);

    // --- head ---
    mlp_kernel<<<NGRAPH, 64, 0, stream>>>(sums, cnt, Wl1, bl1, Wl2, bl2, out);
}